// Round 11
// baseline (26992.603 us; speedup 1.0000x reference)
//
#include <hip/hip_runtime.h>

// FeedbackTransformerKV — persistent kernel, round 11.
// r10 post-mortem: three memory-system fixes (release-semantics, KV bytes,
// XCD placement) were all null => each phase is a SERIAL chain of ~6-8 MALL
// round-trips (~1.5us each) and none were removed. This round hides them:
// each block runs TWO independent batch-group contexts (g and g+8, same
// weight slice) software-pipelined with a split arrive/wait barrier — the
// sync+visibility round-trips of context A complete under context B's body.
// 64 blocks = 8 gp x 8 cs, 1024 threads. Math identical to r10.

#define S_ 128
#define B_ 16
#define D_ 512
#define H_ 8
#define DK_ 64
#define DFF_ 2048
#define L_ 4
#define P_ 4096

#define NBLK 64
#define NTHR 1024

struct FtkvParams {
  const float *x_seq, *w_query, *qpb, *kpe, *w_out, *b_out;
  const float *ln1_g, *ln1_b, *ln2_g, *ln2_b;
  const float *w_ff1, *b_ff1, *w_ff2, *b_ff2;
  const float *norm_g, *norm_b, *comb_w, *w_key, *w_value;
  float *out;
  float *dpart;     // [16 g][8 cs][512]
  float *dpart2;    // [16 g][8 cs][512]
  unsigned *memK;   // [16 g][8 h][128 slot][32 dw]  bf16 pairs
  unsigned *memV;   // [16 g][8 h][128 slot][32 dw]
  const uint4 *wqp;  // per layer [64 k8][512 col] (uint4 = 8 bf16 along k)
  const uint4 *wop;
  const uint4 *w1p;  // per layer [64 k8][2048]
  const uint4 *w2p;  // per layer [256 k8][512]
  const uint4 *wkp;  // [64 k8][512]
  const uint4 *wvp;
  unsigned int *bar;
};

__device__ __forceinline__ float cload(const float *p_) {
  return __hip_atomic_load(p_, __ATOMIC_RELAXED, __HIP_MEMORY_SCOPE_AGENT);
}
__device__ __forceinline__ void cstore(float *p_, float v) {
  __hip_atomic_store(p_, v, __ATOMIC_RELAXED, __HIP_MEMORY_SCOPE_AGENT);
}

__device__ __forceinline__ float waveRedSum(float v) {
#pragma unroll
  for (int off = 32; off; off >>= 1) v += __shfl_xor(v, off, 64);
  return v;
}
__device__ __forceinline__ float waveRedMax(float v) {
#pragma unroll
  for (int off = 32; off; off >>= 1) v = fmaxf(v, __shfl_xor(v, off, 64));
  return v;
}

#define UNPK(w, flo, fhi)                                     \
  float flo = __uint_as_float((unsigned)(w) << 16);           \
  float fhi = __uint_as_float((unsigned)(w) & 0xffff0000u);

__device__ __forceinline__ float dot8(const float *z, uint4 w) {
  UNPK(w.x, a0, a1); UNPK(w.y, b0, b1);
  UNPK(w.z, c0, c1); UNPK(w.w, d0, d1);
  return ((z[0] * a0 + z[1] * a1) + (z[2] * b0 + z[3] * b1)) +
         ((z[4] * c0 + z[5] * c1) + (z[6] * d0 + z[7] * d1));
}

// Split barrier: arrive bumps the group's counter; wait polls for ep*8.
__device__ __forceinline__ void arrive(unsigned *arr, unsigned &ep) {
  __syncthreads();  // drain this block's sc1 partial stores (vmcnt)
  if (threadIdx.x == 0)
    __hip_atomic_fetch_add(arr, 1u, __ATOMIC_RELAXED,
                           __HIP_MEMORY_SCOPE_AGENT);
  ++ep;
}
__device__ __forceinline__ void waitbar(unsigned *arr, unsigned ep) {
  if (threadIdx.x == 0) {
    while (__hip_atomic_load(arr, __ATOMIC_RELAXED,
                             __HIP_MEMORY_SCOPE_AGENT) < ep * 8u)
      __builtin_amdgcn_s_sleep(1);
  }
  __syncthreads();
}

__global__ void ftkv_init(unsigned *bar) {
  for (int i = threadIdx.x; i < 4096; i += 256) bar[i] = 0u;
}

__device__ __forceinline__ unsigned bf16rne(float x) {
  unsigned b = __float_as_uint(x);
  return (b + 0x7fffu + ((b >> 16) & 1u)) >> 16;
}

// src[K][N] fp32 -> dst dwords laid out as [K/8][N][4]
__global__ void ftkv_pack(const float *src, unsigned *dst, int K, int N) {
  int total = (K / 2) * N;
  int n4 = N * 4;
  for (int i = blockIdx.x * blockDim.x + threadIdx.x; i < total;
       i += gridDim.x * blockDim.x) {
    int k8 = i / n4, rem = i - k8 * n4;
    int col = rem >> 2, q = rem & 3;
    int r0 = 8 * k8 + 2 * q;
    dst[i] = bf16rne(src[(size_t)r0 * N + col]) |
             (bf16rne(src[(size_t)(r0 + 1) * N + col]) << 16);
  }
}

// LN stats: 2 syncthreads, final reduce computed redundantly by all threads.
__device__ __forceinline__ void lnstats(int tid, int lane, int wid, float v,
                                        float *sRed, float &mu, float &rs) {
  __syncthreads();
  if (tid < 512) {
    float s1 = waveRedSum(v), s2 = waveRedSum(v * v);
    if (lane == 0) { sRed[wid] = s1; sRed[8 + wid] = s2; }
  }
  __syncthreads();
  float a = 0.f, c = 0.f;
#pragma unroll
  for (int i = 0; i < 8; ++i) { a += sRed[i]; c += sRed[8 + i]; }
  mu = a * (1.f / 512.f);
  float var = c * (1.f / 512.f) - mu * mu;
  rs = rsqrtf(var + 1e-5f);
}

struct Smem {
  float sZ[512];
  float sP[1024];
  float sH[256];
  float sQ[64], sQB[64], sS[128], sRed[20];
};

// Phase A body: LN1 + qproj + scores + softmax + av + Wout partial store.
__device__ __forceinline__ void bodyA(const FtkvParams &p, Smem &sm, int tid,
                                      int lane, int wid, int t, int l, int g,
                                      int cs, float xr, unsigned *memKb,
                                      unsigned *memVb) {
  float mu, rs;
  lnstats(tid, lane, wid, xr, sm.sRed, mu, rs);
  if (tid < 512)
    sm.sZ[tid] = (xr - mu) * rs * p.ln1_g[l * D_ + tid] +
                 p.ln1_b[l * D_ + tid];
  __syncthreads();
  {
    int d = tid & 63, ks = tid >> 6;
    const uint4 *wq = p.wqp + (size_t)l * 64 * 512 + cs * 64 + d;
    float acc = 0.f;
#pragma unroll
    for (int j = 0; j < 4; ++j) {
      int k8 = ks * 4 + j;
      acc += dot8(&sm.sZ[8 * k8], wq[(size_t)k8 * 512]);
    }
    sm.sP[tid] = acc;
  }
  __syncthreads();
  if (tid < 64) {
    float q = 0.f;
#pragma unroll
    for (int ks = 0; ks < 16; ++ks) q += sm.sP[ks * 64 + tid];
    sm.sQ[tid] = q;
    sm.sQB[tid] = q + p.qpb[(l * H_ + cs) * 64 + tid];
  }
  __syncthreads();
  {
    int j = tid & 127, ds = tid >> 7;
    float acc = 0.f;
    if (j < t) {
      uint4 mku = ((const uint4 *)(memKb + (size_t)j * 32))[ds];
      const float4 *kp = (const float4 *)(p.kpe +
          (((size_t)l * P_ + (P_ - t + j)) * H_ + cs) * 64 + ds * 8);
      float4 b0 = kp[0], b1 = kp[1];
      UNPK(mku.x, k0, k1); UNPK(mku.y, k2, k3);
      UNPK(mku.z, k4, k5); UNPK(mku.w, k6, k7);
      const float *qb = &sm.sQB[ds * 8], *qr = &sm.sQ[ds * 8];
      acc = (qb[0] * k0 + qb[1] * k1 + qb[2] * k2 + qb[3] * k3) +
            (qb[4] * k4 + qb[5] * k5 + qb[6] * k6 + qb[7] * k7) +
            (qr[0] * b0.x + qr[1] * b0.y + qr[2] * b0.z + qr[3] * b0.w) +
            (qr[4] * b1.x + qr[5] * b1.y + qr[6] * b1.z + qr[7] * b1.w);
    }
    sm.sP[tid] = acc;
  }
  __syncthreads();
  if (tid < 128) {
    float sc =
        ((sm.sP[tid] + sm.sP[tid + 128]) + (sm.sP[tid + 256] + sm.sP[tid + 384])) +
        ((sm.sP[tid + 512] + sm.sP[tid + 640]) + (sm.sP[tid + 768] + sm.sP[tid + 896]));
    sm.sS[tid] = (tid < t) ? sc * 0.125f : -1e30f;
  }
  __syncthreads();
  if (tid < 64) {
    float m = waveRedMax(fmaxf(sm.sS[tid], sm.sS[tid + 64]));
    if (tid == 0) sm.sRed[18] = m;
  }
  __syncthreads();
  if (tid < 128)
    sm.sS[tid] = (tid < t) ? __expf(sm.sS[tid] - sm.sRed[18]) : 0.f;
  __syncthreads();
  if (tid < 64) {
    float s = waveRedSum(sm.sS[tid] + sm.sS[tid + 64]);
    if (tid == 0) sm.sRed[19] = s;
  }
  __syncthreads();
  {
    int d = tid & 63, js = tid >> 6;
    int j0 = js * 8, j1 = (j0 + 8 < t) ? (j0 + 8) : t;
    float acc = 0.f;
    const ushort *mv = (const ushort *)memVb;
    for (int j = j0; j < j1; ++j) {
      float vv = __uint_as_float(((unsigned)mv[(size_t)j * 64 + d]) << 16);
      acc += sm.sS[j] * vv;
    }
    sm.sP[tid] = acc;
  }
  __syncthreads();
  if (tid < 64) {
    float a = 0.f;
#pragma unroll
    for (int js = 0; js < 16; ++js) a += sm.sP[js * 64 + tid];
    sm.sQ[tid] = a / sm.sRed[19];
  }
  __syncthreads();
  {
    int col = tid & 511, ks = tid >> 9;
    const uint4 *wo = p.wop + (size_t)l * 64 * 512 + col;
    float acc = 0.f;
#pragma unroll
    for (int j = 0; j < 4; ++j) {
      int k8l = ks * 4 + j;
      acc += dot8(&sm.sQ[8 * k8l], wo[(size_t)(cs * 8 + k8l) * 512]);
    }
    sm.sP[tid] = acc;
  }
  __syncthreads();
  if (tid < 512)
    cstore(&p.dpart[((size_t)g * 8 + cs) * D_ + tid],
           sm.sP[tid] + sm.sP[512 + tid]);
}

// Phase B body: (optional Wout apply done by caller) LN2 + FF1 + FF2 partial.
__device__ __forceinline__ void bodyB(const FtkvParams &p, Smem &sm, int tid,
                                      int lane, int wid, int l, int g, int cs,
                                      float xr) {
  float mu, rs;
  lnstats(tid, lane, wid, xr, sm.sRed, mu, rs);
  if (tid < 512)
    sm.sZ[tid] = (xr - mu) * rs * p.ln2_g[l * D_ + tid] +
                 p.ln2_b[l * D_ + tid];
  __syncthreads();
  {
    int c = tid & 255, ks = tid >> 8;
    const uint4 *w1 = p.w1p + (size_t)l * 64 * DFF_ + cs * 256 + c;
    float acc = 0.f;
#pragma unroll 8
    for (int j = 0; j < 16; ++j) {
      int k8 = ks * 16 + j;
      acc += dot8(&sm.sZ[8 * k8], w1[(size_t)k8 * DFF_]);
    }
    sm.sP[tid] = acc;
  }
  __syncthreads();
  if (tid < 256) {
    float h = ((sm.sP[tid] + sm.sP[256 + tid]) +
               (sm.sP[512 + tid] + sm.sP[768 + tid])) +
              p.b_ff1[l * DFF_ + cs * 256 + tid];
    sm.sH[tid] = fmaxf(h, 0.f);
  }
  __syncthreads();
  {
    int col = tid & 511, ks = tid >> 9;
    const uint4 *w2 = p.w2p + (size_t)l * 256 * 512 + col;
    float acc = 0.f;
#pragma unroll 8
    for (int j = 0; j < 16; ++j) {
      int k8l = ks * 16 + j;
      acc += dot8(&sm.sH[8 * k8l], w2[(size_t)(cs * 32 + k8l) * 512]);
    }
    sm.sP[tid] = acc;
  }
  __syncthreads();
  if (tid < 512)
    cstore(&p.dpart2[((size_t)g * 8 + cs) * D_ + tid],
           sm.sP[tid] + sm.sP[512 + tid]);
}

// Phase E body: consume FF(3) partials, KV proj of mem, out[t], next-x.
__device__ __forceinline__ void bodyE(const FtkvParams &p, Smem &sm, int tid,
                                      int lane, int wid, int t, int g, int cs,
                                      float &xr, float &mr, float comb0,
                                      float comb4, unsigned *memKb,
                                      unsigned *memVb) {
  if (tid < 512) {
    float s = p.b_ff2[3 * D_ + tid];
#pragma unroll
    for (int c2 = 0; c2 < 8; ++c2)
      s += cload(&p.dpart2[((size_t)g * 8 + c2) * D_ + tid]);
    xr += s;
    mr += comb4 * xr;
    sm.sZ[tid] = mr;
  }
  __syncthreads();
  {
    int kv = tid >> 9, r = tid & 511, d = r & 63, ks = r >> 6;
    const uint4 *w4 = (kv ? p.wvp : p.wkp) + cs * 64 + d;
    float acc = 0.f;
#pragma unroll
    for (int j = 0; j < 8; ++j) {
      int k8 = ks * 8 + j;
      acc += dot8(&sm.sZ[8 * k8], w4[(size_t)k8 * 512]);
    }
    sm.sP[tid] = acc;
  }
  __syncthreads();
  if (tid < 128) {
    int kv = tid >> 6, d = tid & 63;
    float v = 0.f;
#pragma unroll
    for (int ks = 0; ks < 8; ++ks) v += sm.sP[kv * 512 + ks * 64 + d];
    sm.sS[tid] = v;
  }
  __syncthreads();
  if (tid < 64) {
    int kv = tid >> 5, d2 = tid & 31;
    float lo = sm.sS[kv * 64 + 2 * d2], hi = sm.sS[kv * 64 + 2 * d2 + 1];
    unsigned pk = bf16rne(lo) | (bf16rne(hi) << 16);
    unsigned *dst = kv ? memVb : memKb;
    dst[(size_t)t * 32 + d2] = pk;
  }
  {
    float mu, rs;
    lnstats(tid, lane, wid, xr, sm.sRed, mu, rs);
    if (tid < 512 && (tid >> 6) == cs)
      p.out[((size_t)t * B_ + g) * D_ + tid] =
          (xr - mu) * rs * p.norm_g[tid] + p.norm_b[tid];
  }
  if (t + 1 < S_ && tid < 512) {
    xr = p.x_seq[((size_t)(t + 1) * B_ + g) * D_ + tid];
    mr = comb0 * xr;
  }
}

__global__ __launch_bounds__(NTHR, 4) void ftkv_main(FtkvParams p) {
  const int bid = blockIdx.x;
  const int tid = threadIdx.x;
  const int lane = tid & 63, wid = tid >> 6;
  const int gp = bid >> 3;  // group pair id 0..7
  const int cs = bid & 7;   // col-slice == head

  __shared__ Smem sm;

  const int gA = gp, gB = gp + 8;  // the two batch-group contexts
  unsigned *arrA = p.bar + gA * 32;
  unsigned *arrB = p.bar + gB * 32;
  unsigned epA = 0, epB = 0;

  float cw0 = p.comb_w[0], cw1 = p.comb_w[1], cw2 = p.comb_w[2],
        cw3 = p.comb_w[3], cw4 = p.comb_w[4];
  float cm = fmaxf(fmaxf(fmaxf(cw0, cw1), fmaxf(cw2, cw3)), cw4);
  float e0 = __expf(cw0 - cm), e1 = __expf(cw1 - cm), e2 = __expf(cw2 - cm),
        e3 = __expf(cw3 - cm), e4 = __expf(cw4 - cm);
  float einv = 1.0f / (e0 + e1 + e2 + e3 + e4);
  float comb0 = e0 * einv, comb1 = e1 * einv, comb2 = e2 * einv,
        comb3 = e3 * einv, comb4 = e4 * einv;

  float xrA = 0.f, mrA = 0.f, xrB = 0.f, mrB = 0.f;
  if (tid < 512) {
    xrA = p.x_seq[gA * D_ + tid];
    mrA = comb0 * xrA;
    xrB = p.x_seq[gB * D_ + tid];
    mrB = comb0 * xrB;
  }

  unsigned *memKbA = p.memK + ((size_t)(gA * H_ + cs)) * S_ * 32;
  unsigned *memVbA = p.memV + ((size_t)(gA * H_ + cs)) * S_ * 32;
  unsigned *memKbB = p.memK + ((size_t)(gB * H_ + cs)) * S_ * 32;
  unsigned *memVbB = p.memV + ((size_t)(gB * H_ + cs)) * S_ * 32;

  for (int t = 0; t < S_; ++t) {
    for (int l = 0; l < L_; ++l) {
      const float cl = (l == 1) ? comb1 : (l == 2) ? comb2 : comb3;

      if (t > 0) {
        // ---- A pair ----
        waitbar(arrA, epA);  // post-B(l-1) (or no-op at l==0)
        if (l > 0 && tid < 512) {
          float s = p.b_ff2[(l - 1) * D_ + tid];
#pragma unroll
          for (int c2 = 0; c2 < 8; ++c2)
            s += cload(&p.dpart2[((size_t)gA * 8 + c2) * D_ + tid]);
          xrA += s;
          mrA += cl * xrA;
        }
        bodyA(p, sm, tid, lane, wid, t, l, gA, cs, xrA, memKbA, memVbA);
        arrive(arrA, epA);

        waitbar(arrB, epB);
        if (l > 0 && tid < 512) {
          float s = p.b_ff2[(l - 1) * D_ + tid];
#pragma unroll
          for (int c2 = 0; c2 < 8; ++c2)
            s += cload(&p.dpart2[((size_t)gB * 8 + c2) * D_ + tid]);
          xrB += s;
          mrB += cl * xrB;
        }
        bodyA(p, sm, tid, lane, wid, t, l, gB, cs, xrB, memKbB, memVbB);
        arrive(arrB, epB);

        // ---- B pair ----
        waitbar(arrA, epA);  // post-A
        if (tid < 512) {
          float s = p.b_out[l * D_ + tid];
#pragma unroll
          for (int c2 = 0; c2 < 8; ++c2)
            s += cload(&p.dpart[((size_t)gA * 8 + c2) * D_ + tid]);
          xrA += s;
        }
        bodyB(p, sm, tid, lane, wid, l, gA, cs, xrA);
        arrive(arrA, epA);

        waitbar(arrB, epB);
        if (tid < 512) {
          float s = p.b_out[l * D_ + tid];
#pragma unroll
          for (int c2 = 0; c2 < 8; ++c2)
            s += cload(&p.dpart[((size_t)gB * 8 + c2) * D_ + tid]);
          xrB += s;
        }
        bodyB(p, sm, tid, lane, wid, l, gB, cs, xrB);
        arrive(arrB, epB);
      } else {
        // t == 0: no attention; B phases only
        waitbar(arrA, epA);
        if (l > 0 && tid < 512) {
          float s = p.b_ff2[(l - 1) * D_ + tid];
#pragma unroll
          for (int c2 = 0; c2 < 8; ++c2)
            s += cload(&p.dpart2[((size_t)gA * 8 + c2) * D_ + tid]);
          xrA += s;
          mrA += cl * xrA;
        }
        bodyB(p, sm, tid, lane, wid, l, gA, cs, xrA);
        arrive(arrA, epA);

        waitbar(arrB, epB);
        if (l > 0 && tid < 512) {
          float s = p.b_ff2[(l - 1) * D_ + tid];
#pragma unroll
          for (int c2 = 0; c2 < 8; ++c2)
            s += cload(&p.dpart2[((size_t)gB * 8 + c2) * D_ + tid]);
          xrB += s;
          mrB += cl * xrB;
        }
        bodyB(p, sm, tid, lane, wid, l, gB, cs, xrB);
        arrive(arrB, epB);
      }
    } // layers

    // ---- E pair (group-local; wait for post-B(3) partials) ----
    waitbar(arrA, epA);
    bodyE(p, sm, tid, lane, wid, t, gA, cs, xrA, mrA, comb0, comb4, memKbA,
          memVbA);
    waitbar(arrB, epB);
    bodyE(p, sm, tid, lane, wid, t, gB, cs, xrB, mrB, comb0, comb4, memKbB,
          memVbB);
  } // t
}

extern "C" void kernel_launch(void *const *d_in, const int *in_sizes, int n_in,
                              void *d_out, int out_size, void *d_ws,
                              size_t ws_size, hipStream_t stream) {
  (void)in_sizes; (void)n_in; (void)out_size; (void)ws_size;

  FtkvParams p;
  p.x_seq  = (const float *)d_in[0];
  p.w_query = (const float *)d_in[1];
  p.qpb    = (const float *)d_in[2];
  p.kpe    = (const float *)d_in[3];
  p.w_out  = (const float *)d_in[4];
  p.b_out  = (const float *)d_in[5];
  p.ln1_g  = (const float *)d_in[6];
  p.ln1_b  = (const float *)d_in[7];
  p.ln2_g  = (const float *)d_in[8];
  p.ln2_b  = (const float *)d_in[9];
  p.w_ff1  = (const float *)d_in[10];
  p.b_ff1  = (const float *)d_in[11];
  p.w_ff2  = (const float *)d_in[12];
  p.b_ff2  = (const float *)d_in[13];
  p.norm_g = (const float *)d_in[14];
  p.norm_b = (const float *)d_in[15];
  p.comb_w = (const float *)d_in[16];
  p.w_key  = (const float *)d_in[17];
  p.w_value = (const float *)d_in[18];
  p.out = (float *)d_out;

  char *ws = (char *)d_ws;
  p.bar = (unsigned int *)ws; // 16KB
  float *f = (float *)(ws + 16384);
  p.dpart  = f; f += B_ * 8 * D_;
  p.dpart2 = f; f += B_ * 8 * D_;
  unsigned *u = (unsigned *)f;
  p.memK = u; u += B_ * H_ * S_ * 32;  // bf16-pair dwords
  p.memV = u; u += B_ * H_ * S_ * 32;
  unsigned *wqp = u; u += L_ * 256 * 512;
  unsigned *wop = u; u += L_ * 256 * 512;
  unsigned *w1p = u; u += L_ * 256 * DFF_;
  unsigned *w2p = u; u += L_ * 1024 * 512;
  unsigned *wkp = u; u += 256 * 512;
  unsigned *wvp = u; u += 256 * 512;
  p.wqp = (const uint4 *)wqp; p.wop = (const uint4 *)wop;
  p.w1p = (const uint4 *)w1p; p.w2p = (const uint4 *)w2p;
  p.wkp = (const uint4 *)wkp; p.wvp = (const uint4 *)wvp;

  ftkv_init<<<dim3(1), dim3(256), 0, stream>>>(p.bar);
  for (int l = 0; l < L_; ++l) {
    ftkv_pack<<<dim3(256), dim3(256), 0, stream>>>(
        p.w_query + (size_t)l * 512 * 512, wqp + (size_t)l * 256 * 512, 512, 512);
    ftkv_pack<<<dim3(256), dim3(256), 0, stream>>>(
        p.w_out + (size_t)l * 512 * 512, wop + (size_t)l * 256 * 512, 512, 512);
    ftkv_pack<<<dim3(512), dim3(256), 0, stream>>>(
        p.w_ff1 + (size_t)l * 512 * DFF_, w1p + (size_t)l * 256 * DFF_, 512, DFF_);
    ftkv_pack<<<dim3(512), dim3(256), 0, stream>>>(
        p.w_ff2 + (size_t)l * DFF_ * 512, w2p + (size_t)l * 1024 * 512, DFF_, 512);
  }
  ftkv_pack<<<dim3(256), dim3(256), 0, stream>>>(p.w_key, wkp, 512, 512);
  ftkv_pack<<<dim3(256), dim3(256), 0, stream>>>(p.w_value, wvp, 512, 512);
  ftkv_main<<<dim3(NBLK), dim3(NTHR), 0, stream>>>(p);
}

// Round 12
// 11658.412 us; speedup vs baseline: 2.3153x; 2.3153x over previous
//
#include <hip/hip_runtime.h>

// FeedbackTransformerKV — persistent kernel, round 12.
// r11 proved: phase body = ~13us of SERIAL stalls (2us VALU), because every
// __syncthreads drains vmcnt(0) -> each of ~12 stages pays a full memory
// latency before the next can issue. Fix (on r10 base): (1) intra-body
// barriers become lgkmcnt-only ("lbar": LDS-visibility without draining
// global loads); (2) weights/KV/kpe PREFETCHED into registers at phase top,
// latency hidden under LN stages; (3) softmax max/exp/sum fused to one
// single-wave stage. Full drain only at group-barrier arrive + after KV store.

#define S_ 128
#define B_ 16
#define D_ 512
#define H_ 8
#define DK_ 64
#define DFF_ 2048
#define L_ 4
#define P_ 4096

#define NBLK 128
#define NTHR 1024

struct FtkvParams {
  const float *x_seq, *w_query, *qpb, *kpe, *w_out, *b_out;
  const float *ln1_g, *ln1_b, *ln2_g, *ln2_b;
  const float *w_ff1, *b_ff1, *w_ff2, *b_ff2;
  const float *norm_g, *norm_b, *comb_w, *w_key, *w_value;
  float *out;
  float *dpart;     // [16 g][8 cs][512]
  float *dpart2;    // [16 g][8 cs][512]
  unsigned *memK;   // [16 g][8 h][128 slot][32 dw] bf16 pairs
  unsigned *memV;   // [16 g][8 h][128 slot][32 dw]
  const uint4 *wqp;  // per layer [64 k8][512 col] (uint4 = 8 bf16 along k)
  const uint4 *wop;
  const uint4 *w1p;  // per layer [64 k8][2048]
  const uint4 *w2p;  // per layer [256 k8][512]
  const uint4 *wkp;  // [64 k8][512]
  const uint4 *wvp;
  unsigned int *bar;
};

__device__ __forceinline__ float cload(const float *p_) {
  return __hip_atomic_load(p_, __ATOMIC_RELAXED, __HIP_MEMORY_SCOPE_AGENT);
}
__device__ __forceinline__ void cstore(float *p_, float v) {
  __hip_atomic_store(p_, v, __ATOMIC_RELAXED, __HIP_MEMORY_SCOPE_AGENT);
}

__device__ __forceinline__ float waveRedSum(float v) {
#pragma unroll
  for (int off = 32; off; off >>= 1) v += __shfl_xor(v, off, 64);
  return v;
}
__device__ __forceinline__ float waveRedMax(float v) {
#pragma unroll
  for (int off = 32; off; off >>= 1) v = fmaxf(v, __shfl_xor(v, off, 64));
  return v;
}

// Light barrier: LDS producer->consumer visibility WITHOUT draining vmcnt —
// global (weight-prefetch) loads stay in flight across stage boundaries.
__device__ __forceinline__ void lbar() {
  asm volatile("s_waitcnt lgkmcnt(0)" ::: "memory");
  __builtin_amdgcn_s_barrier();
}

#define UNPK(w, flo, fhi)                                     \
  float flo = __uint_as_float((unsigned)(w) << 16);           \
  float fhi = __uint_as_float((unsigned)(w) & 0xffff0000u);

__device__ __forceinline__ float dot8(const float *z, uint4 w) {
  UNPK(w.x, a0, a1); UNPK(w.y, b0, b1);
  UNPK(w.z, c0, c1); UNPK(w.w, d0, d1);
  return ((z[0] * a0 + z[1] * a1) + (z[2] * b0 + z[3] * b1)) +
         ((z[4] * c0 + z[5] * c1) + (z[6] * d0 + z[7] * d1));
}

// Group barrier (8 blocks/group): full drain before arrive; poll arrive ctr.
__device__ __forceinline__ void gbarN(unsigned *arr, unsigned &epoch) {
  __syncthreads();  // drains vmcnt -> sc1 partial stores visible
  const unsigned e = ++epoch;
  if (threadIdx.x == 0) {
    __hip_atomic_fetch_add(arr, 1u, __ATOMIC_RELAXED,
                           __HIP_MEMORY_SCOPE_AGENT);
    while (__hip_atomic_load(arr, __ATOMIC_RELAXED,
                             __HIP_MEMORY_SCOPE_AGENT) < e * 8u)
      __builtin_amdgcn_s_sleep(1);
  }
  __syncthreads();
}

__global__ void ftkv_init(unsigned *bar) {
  for (int i = threadIdx.x; i < 4096; i += 256) bar[i] = 0u;
}

__device__ __forceinline__ unsigned bf16rne(float x) {
  unsigned b = __float_as_uint(x);
  return (b + 0x7fffu + ((b >> 16) & 1u)) >> 16;
}

// src[K][N] fp32 -> dst dwords laid out as [K/8][N][4]
__global__ void ftkv_pack(const float *src, unsigned *dst, int K, int N) {
  int total = (K / 2) * N;
  int n4 = N * 4;
  for (int i = blockIdx.x * blockDim.x + threadIdx.x; i < total;
       i += gridDim.x * blockDim.x) {
    int k8 = i / n4, rem = i - k8 * n4;
    int col = rem >> 2, q = rem & 3;
    int r0 = 8 * k8 + 2 * q;
    dst[i] = bf16rne(src[(size_t)r0 * N + col]) |
             (bf16rne(src[(size_t)(r0 + 1) * N + col]) << 16);
  }
}

struct Smem {
  float sZ[512];
  float sP[1024];
  float sH[256];
  float sQ[64], sQB[64], sS[128], sRed[24];
};

// LN stats with light barriers; all threads get mu/rs redundantly.
__device__ __forceinline__ void lnstats(int tid, int lane, int wid, float v,
                                        float *sRed, float &mu, float &rs) {
  lbar();  // WAR: prior readers of sRed done
  if (tid < 512) {
    float s1 = waveRedSum(v), s2 = waveRedSum(v * v);
    if (lane == 0) { sRed[wid] = s1; sRed[8 + wid] = s2; }
  }
  lbar();
  float a = 0.f, c = 0.f;
#pragma unroll
  for (int i = 0; i < 8; ++i) { a += sRed[i]; c += sRed[8 + i]; }
  mu = a * (1.f / 512.f);
  float var = c * (1.f / 512.f) - mu * mu;
  rs = rsqrtf(var + 1e-5f);
}

__global__ __launch_bounds__(NTHR, 4) void ftkv_main(FtkvParams p) {
  const int bid = blockIdx.x;
  const int tid = threadIdx.x;
  const int lane = tid & 63, wid = tid >> 6;
  const int g = bid >> 3;  // batch element (group)
  const int cs = bid & 7;  // col-slice == head

  __shared__ Smem sm;

  unsigned *garr = p.bar + g * 32;
  unsigned gep = 0;

  float cw0 = p.comb_w[0], cw1 = p.comb_w[1], cw2 = p.comb_w[2],
        cw3 = p.comb_w[3], cw4 = p.comb_w[4];
  float cm = fmaxf(fmaxf(fmaxf(cw0, cw1), fmaxf(cw2, cw3)), cw4);
  float e0 = __expf(cw0 - cm), e1 = __expf(cw1 - cm), e2 = __expf(cw2 - cm),
        e3 = __expf(cw3 - cm), e4 = __expf(cw4 - cm);
  float einv = 1.0f / (e0 + e1 + e2 + e3 + e4);
  float comb0 = e0 * einv, comb1 = e1 * einv, comb2 = e2 * einv,
        comb3 = e3 * einv, comb4 = e4 * einv;

  float xr = 0.f, mr = 0.f;
  if (tid < 512) {
    xr = p.x_seq[g * D_ + tid];
    mr = comb0 * xr;
  }

  unsigned *memKb = p.memK + ((size_t)(g * H_ + cs)) * S_ * 32;
  unsigned *memVb = p.memV + ((size_t)(g * H_ + cs)) * S_ * 32;

  // thread role decompositions (constant across phases)
  const int d6 = tid & 63, ks16 = tid >> 6;   // 64 cols x 16 k-slices
  const int j7 = tid & 127, ds8 = tid >> 7;   // 128 j x 8 d-slices
  const int col9 = tid & 511, ks2 = tid >> 9; // 512 cols x 2 k-slices
  const int c8 = tid & 255, ksb = tid >> 8;   // 256 cols x 4 k-slices

  for (int t = 0; t < S_; ++t) {
    for (int l = 0; l < L_; ++l) {
      const float cl = (l == 1) ? comb1 : (l == 2) ? comb2 : comb3;

      // ---- entry: apply FF(l-1) partials ----
      if (l > 0 && tid < 512) {
        float s = p.b_ff2[(l - 1) * D_ + tid];
#pragma unroll
        for (int c2 = 0; c2 < 8; ++c2)
          s += cload(&p.dpart2[((size_t)g * 8 + c2) * D_ + tid]);
        xr += s;
        mr += cl * xr;
      }

      // =================== Phase A: attention (t>0) =====================
      if (t > 0) {
        // ---- prefetch (independent of all LN/exchange stages) ----
        uint4 wq[4], wo[4];
        {
          const uint4 *wqp = p.wqp + (size_t)l * 64 * 512 + cs * 64 + d6;
#pragma unroll
          for (int j = 0; j < 4; ++j) wq[j] = wqp[(size_t)(ks16 * 4 + j) * 512];
          const uint4 *wop = p.wop + (size_t)l * 64 * 512 + col9;
#pragma unroll
          for (int j = 0; j < 4; ++j)
            wo[j] = wop[(size_t)(cs * 8 + ks2 * 4 + j) * 512];
        }
        uint4 mku = ((const uint4 *)(memKb + (size_t)j7 * 32))[ds8];
        int kidx = P_ - t + j7;
        kidx = kidx < 0 ? 0 : (kidx > P_ - 1 ? P_ - 1 : kidx);
        const float4 *kpp = (const float4 *)(p.kpe +
            (((size_t)l * P_ + kidx) * H_ + cs) * 64 + ds8 * 8);
        float4 kp0 = kpp[0], kp1 = kpp[1];
        unsigned mvp[8];
        {
#pragma unroll
          for (int jj = 0; jj < 8; ++jj)
            mvp[jj] = memVb[(size_t)(ks16 * 8 + jj) * 32 + (d6 >> 1)];
        }

        float mu, rs;
        lnstats(tid, lane, wid, xr, sm.sRed, mu, rs);
        if (tid < 512)
          sm.sZ[tid] = (xr - mu) * rs * p.ln1_g[l * D_ + tid] +
                       p.ln1_b[l * D_ + tid];
        lbar();
        // qproj
        {
          float acc = 0.f;
#pragma unroll
          for (int j = 0; j < 4; ++j)
            acc += dot8(&sm.sZ[8 * (ks16 * 4 + j)], wq[j]);
          sm.sP[tid] = acc;
        }
        lbar();
        if (tid < 64) {
          float q = 0.f;
#pragma unroll
          for (int ks = 0; ks < 16; ++ks) q += sm.sP[ks * 64 + tid];
          sm.sQ[tid] = q;
          sm.sQB[tid] = q + p.qpb[(l * H_ + cs) * 64 + tid];
        }
        lbar();
        // scores (unconditional; masked at merge)
        {
          UNPK(mku.x, k0, k1); UNPK(mku.y, k2, k3);
          UNPK(mku.z, k4, k5); UNPK(mku.w, k6, k7);
          const float *qb = &sm.sQB[ds8 * 8], *qr = &sm.sQ[ds8 * 8];
          float acc =
              (qb[0] * k0 + qb[1] * k1 + qb[2] * k2 + qb[3] * k3) +
              (qb[4] * k4 + qb[5] * k5 + qb[6] * k6 + qb[7] * k7) +
              (qr[0] * kp0.x + qr[1] * kp0.y + qr[2] * kp0.z + qr[3] * kp0.w) +
              (qr[4] * kp1.x + qr[5] * kp1.y + qr[6] * kp1.z + qr[7] * kp1.w);
          sm.sP[tid] = acc;
        }
        lbar();
        if (tid < 128) {
          float sc = ((sm.sP[tid] + sm.sP[tid + 128]) +
                      (sm.sP[tid + 256] + sm.sP[tid + 384])) +
                     ((sm.sP[tid + 512] + sm.sP[tid + 640]) +
                      (sm.sP[tid + 768] + sm.sP[tid + 896]));
          sm.sS[tid] = (tid < t) ? sc * 0.125f : -1e30f;
        }
        lbar();
        // softmax: fused max/exp/sum in one wave
        if (tid < 64) {
          float a0 = sm.sS[tid], a1 = sm.sS[tid + 64];
          float m = waveRedMax(fmaxf(a0, a1));
          float ee0 = __expf(a0 - m), ee1 = __expf(a1 - m);
          float s = waveRedSum(ee0 + ee1);
          sm.sS[tid] = ee0;
          sm.sS[64 + tid] = ee1;
          if (tid == 0) sm.sRed[19] = s;
        }
        lbar();
        // av (sS[j]=0 for j>=t, so unconditional)
        {
          float acc = 0.f;
#pragma unroll
          for (int jj = 0; jj < 8; ++jj) {
            UNPK(mvp[jj], v0, v1);
            float vv = (d6 & 1) ? v1 : v0;
            acc += sm.sS[ks16 * 8 + jj] * vv;
          }
          sm.sP[tid] = acc;
        }
        lbar();
        if (tid < 64) {
          float a = 0.f;
#pragma unroll
          for (int js = 0; js < 16; ++js) a += sm.sP[js * 64 + tid];
          sm.sQ[tid] = a / sm.sRed[19];
        }
        lbar();
        // Wout partial
        {
          float acc = 0.f;
#pragma unroll
          for (int j = 0; j < 4; ++j)
            acc += dot8(&sm.sQ[8 * (ks2 * 4 + j)], wo[j]);
          sm.sP[tid] = acc;
        }
        lbar();
        if (tid < 512)
          cstore(&p.dpart[((size_t)g * 8 + cs) * D_ + tid],
                 sm.sP[tid] + sm.sP[512 + tid]);
        gbarN(garr, gep);

        // apply Wout partials
        if (tid < 512) {
          float s = p.b_out[l * D_ + tid];
#pragma unroll
          for (int c2 = 0; c2 < 8; ++c2)
            s += cload(&p.dpart[((size_t)g * 8 + c2) * D_ + tid]);
          xr += s;
        }
      }

      // =================== Phase B: LN2 + FF1 + FF2 =====================
      {
        // prefetch FF1 weights
        uint4 w1r[16];
        {
          const uint4 *w1 = p.w1p + (size_t)l * 64 * DFF_ + cs * 256 + c8;
#pragma unroll
          for (int j = 0; j < 16; ++j)
            w1r[j] = w1[(size_t)(ksb * 16 + j) * DFF_];
        }
        float mu, rs;
        lnstats(tid, lane, wid, xr, sm.sRed, mu, rs);
        if (tid < 512)
          sm.sZ[tid] = (xr - mu) * rs * p.ln2_g[l * D_ + tid] +
                       p.ln2_b[l * D_ + tid];
        lbar();
        {
          float acc = 0.f;
#pragma unroll
          for (int j = 0; j < 16; ++j)
            acc += dot8(&sm.sZ[8 * (ksb * 16 + j)], w1r[j]);
          sm.sP[tid] = acc;
        }
        // prefetch FF2 weights (overlaps sH stage)
        uint4 w2r[16];
        {
          const uint4 *w2 = p.w2p + (size_t)l * 256 * 512 + col9;
#pragma unroll
          for (int j = 0; j < 16; ++j)
            w2r[j] = w2[(size_t)(cs * 32 + ks2 * 16 + j) * 512];
        }
        lbar();
        if (tid < 256) {
          float h = ((sm.sP[tid] + sm.sP[256 + tid]) +
                     (sm.sP[512 + tid] + sm.sP[768 + tid])) +
                    p.b_ff1[l * DFF_ + cs * 256 + tid];
          sm.sH[tid] = fmaxf(h, 0.f);
        }
        lbar();
        {
          float acc = 0.f;
#pragma unroll
          for (int j = 0; j < 16; ++j)
            acc += dot8(&sm.sH[8 * (ks2 * 16 + j)], w2r[j]);
          sm.sP[tid] = acc;
        }
        lbar();
        if (tid < 512)
          cstore(&p.dpart2[((size_t)g * 8 + cs) * D_ + tid],
                 sm.sP[tid] + sm.sP[512 + tid]);
      }
      gbarN(garr, gep);
    } // layers

    // ====== Phase E (group-local): KV slot t; out[t]; next x ====
    {
      const int kv = tid >> 9, rE = tid & 511, dE = rE & 63, ks8 = rE >> 6;
      uint4 wkv[8];
      {
        const uint4 *w4 = (kv ? p.wvp : p.wkp) + cs * 64 + dE;
#pragma unroll
        for (int j = 0; j < 8; ++j) wkv[j] = w4[(size_t)(ks8 * 8 + j) * 512];
      }
      if (tid < 512) {
        float s = p.b_ff2[3 * D_ + tid];
#pragma unroll
        for (int c2 = 0; c2 < 8; ++c2)
          s += cload(&p.dpart2[((size_t)g * 8 + c2) * D_ + tid]);
        xr += s;
        mr += comb4 * xr;
        sm.sZ[tid] = mr;
      }
      lbar();
      {
        float acc = 0.f;
#pragma unroll
        for (int j = 0; j < 8; ++j)
          acc += dot8(&sm.sZ[8 * (ks8 * 8 + j)], wkv[j]);
        sm.sP[tid] = acc;
      }
      lbar();
      if (tid < 128) {
        int kv2 = tid >> 6, d = tid & 63;
        float v = 0.f;
#pragma unroll
        for (int ks = 0; ks < 8; ++ks) v += sm.sP[kv2 * 512 + ks * 64 + d];
        sm.sS[tid] = v;
      }
      lbar();
      if (tid < 64) {
        int kv2 = tid >> 5, d2 = tid & 31;
        float lo = sm.sS[kv2 * 64 + 2 * d2], hi = sm.sS[kv2 * 64 + 2 * d2 + 1];
        unsigned pk = bf16rne(lo) | (bf16rne(hi) << 16);
        unsigned *dst = kv2 ? memVb : memKb;
        dst[(size_t)t * 32 + d2] = pk;
      }
      __syncthreads();  // drain KV stores: next step's prefetch reads them
      float mu, rs;
      lnstats(tid, lane, wid, xr, sm.sRed, mu, rs);
      if (tid < 512 && (tid >> 6) == cs)
        p.out[((size_t)t * B_ + g) * D_ + tid] =
            (xr - mu) * rs * p.norm_g[tid] + p.norm_b[tid];
      if (t + 1 < S_ && tid < 512) {
        xr = p.x_seq[((size_t)(t + 1) * B_ + g) * D_ + tid];
        mr = comb0 * xr;
      }
    }
    // no barrier: E is group-local; next gbarN orders the exchange
  } // t
}

extern "C" void kernel_launch(void *const *d_in, const int *in_sizes, int n_in,
                              void *d_out, int out_size, void *d_ws,
                              size_t ws_size, hipStream_t stream) {
  (void)in_sizes; (void)n_in; (void)out_size; (void)ws_size;

  FtkvParams p;
  p.x_seq  = (const float *)d_in[0];
  p.w_query = (const float *)d_in[1];
  p.qpb    = (const float *)d_in[2];
  p.kpe    = (const float *)d_in[3];
  p.w_out  = (const float *)d_in[4];
  p.b_out  = (const float *)d_in[5];
  p.ln1_g  = (const float *)d_in[6];
  p.ln1_b  = (const float *)d_in[7];
  p.ln2_g  = (const float *)d_in[8];
  p.ln2_b  = (const float *)d_in[9];
  p.w_ff1  = (const float *)d_in[10];
  p.b_ff1  = (const float *)d_in[11];
  p.w_ff2  = (const float *)d_in[12];
  p.b_ff2  = (const float *)d_in[13];
  p.norm_g = (const float *)d_in[14];
  p.norm_b = (const float *)d_in[15];
  p.comb_w = (const float *)d_in[16];
  p.w_key  = (const float *)d_in[17];
  p.w_value = (const float *)d_in[18];
  p.out = (float *)d_out;

  char *ws = (char *)d_ws;
  p.bar = (unsigned int *)ws; // 16KB
  float *f = (float *)(ws + 16384);
  p.dpart  = f; f += B_ * 8 * D_;
  p.dpart2 = f; f += B_ * 8 * D_;
  unsigned *u = (unsigned *)f;
  p.memK = u; u += B_ * H_ * S_ * 32;  // bf16-pair dwords
  p.memV = u; u += B_ * H_ * S_ * 32;
  unsigned *wqp = u; u += L_ * 256 * 512;
  unsigned *wop = u; u += L_ * 256 * 512;
  unsigned *w1p = u; u += L_ * 256 * DFF_;
  unsigned *w2p = u; u += L_ * 1024 * 512;
  unsigned *wkp = u; u += 256 * 512;
  unsigned *wvp = u; u += 256 * 512;
  p.wqp = (const uint4 *)wqp; p.wop = (const uint4 *)wop;
  p.w1p = (const uint4 *)w1p; p.w2p = (const uint4 *)w2p;
  p.wkp = (const uint4 *)wkp; p.wvp = (const uint4 *)wvp;

  ftkv_init<<<dim3(1), dim3(256), 0, stream>>>(p.bar);
  for (int l = 0; l < L_; ++l) {
    ftkv_pack<<<dim3(256), dim3(256), 0, stream>>>(
        p.w_query + (size_t)l * 512 * 512, wqp + (size_t)l * 256 * 512, 512, 512);
    ftkv_pack<<<dim3(256), dim3(256), 0, stream>>>(
        p.w_out + (size_t)l * 512 * 512, wop + (size_t)l * 256 * 512, 512, 512);
    ftkv_pack<<<dim3(512), dim3(256), 0, stream>>>(
        p.w_ff1 + (size_t)l * 512 * DFF_, w1p + (size_t)l * 256 * DFF_, 512, DFF_);
    ftkv_pack<<<dim3(512), dim3(256), 0, stream>>>(
        p.w_ff2 + (size_t)l * DFF_ * 512, w2p + (size_t)l * 1024 * 512, DFF_, 512);
  }
  ftkv_pack<<<dim3(256), dim3(256), 0, stream>>>(p.w_key, wkp, 512, 512);
  ftkv_pack<<<dim3(256), dim3(256), 0, stream>>>(p.w_value, wvp, 512, 512);
  ftkv_main<<<dim3(NBLK), dim3(NTHR), 0, stream>>>(p);
}